// Round 14
// baseline (55.641 us; speedup 1.0000x reference)
//
#include <hip/hip_runtime.h>

#define EPSV 2.220446049250313e-16f
#define C3F  (-0.09016844005555896f)   // -log2(e)/16
#define SSCL 0.1201122408786449f       // sqrt(log2(e)/100)
#define EPSS (EPSV * SSCL)

typedef float f2 __attribute__((ext_vector_type(2)));
typedef float f4 __attribute__((ext_vector_type(4)));

// R14 = R11 (best, 30.5us) wrapped in a x2 rep loop for DIAGNOSIS ONLY:
// rep1 recomputes everything (jittered input defeats CSE/LICM) and stores to a
// discarded ws region, doubling kernel duration past the harness's 39us fills
// so ncut_main re-enters the profiled top-5 with a full counter row.
// Same grid/LDS/VGPR/occupancy as R11 -> counters represent the real kernel.

__global__ __launch_bounds__(256) void ncut_main(const float* __restrict__ batch,
                                                 const float* __restrict__ preds,
                                                 float* __restrict__ wsAll) {
    constexpr int LS = 38;             // LDS row stride (floats)
    constexpr int PLANE = 38 * LS;     // 1444 floats per padded slice
    __shared__ float sAll[7 * PLANE];  // plane 0: scaled batch; planes 1..6: preds
    __shared__ float redBuf[4][12];

    const int tid = threadIdx.x;
    const int bx  = blockIdx.x;
    const int oz  = bx >> 8;           // 0..3
    const int b   = (bx >> 5) & 7;     // batch
    const int d   = bx & 31;           // center z-slice

    const int z   = d + oz;            // partner slice (never <0)
    const bool zok = (z < 32);

    #pragma unroll 1
    for (int rep = 0; rep < 2; ++rep) {
        __syncthreads();               // protect LDS reuse across reps

        // ---- init planes to pad value (7*1444/4 = 2527 f4) ----
        {
            f4* a4 = (f4*)sAll;
            const f4 bpad = {EPSS, EPSS, EPSS, EPSS};
            const f4 ppad = {EPSV, EPSV, EPSV, EPSV};
            for (int i = tid; i < 2527; i += 256) a4[i] = (i < 361) ? bpad : ppad;
        }
        __syncthreads();

        // ---- copy interiors: coalesced f4 loads ----
        const int hh = tid >> 3;           // 0..31
        const int j4 = (tid & 7) << 2;     // 0,4,...,28
        if (zok) {
            const float* bsrc = batch + ((size_t)b * 32 + z) * 1024 + hh * 32 + j4;
            const float* psrc = preds + ((size_t)b * 6 * 32 + z) * 1024 + hh * 32 + j4;
            {
                f4 v = *(const f4*)bsrc;
                v *= SSCL;
                float* dst = sAll + (hh + 3) * LS + (j4 + 3);
                dst[0] = v.x; dst[1] = v.y; dst[2] = v.z; dst[3] = v.w;
            }
            #pragma unroll
            for (int p = 0; p < 6; ++p) {
                f4 v = *(const f4*)(psrc + (size_t)p * 32768);
                float* dst = sAll + (p + 1) * PLANE + (hh + 3) * LS + (j4 + 3);
                dst[0] = v.x; dst[1] = v.y; dst[2] = v.z; dst[3] = v.w;
            }
        }

        const int h  = hh;                 // row
        const int v0 = j4;                 // voxel start
        f4 Ip = *(const f4*)&batch[((size_t)b * 32 + d) * 1024 + h * 32 + v0];
        Ip *= SSCL;
        Ip += (float)rep * 1e-7f;          // defeat CSE/LICM across reps (rep0 exact)

        __syncthreads();

        f4 wsum = {};
        f4 acc[6] = {};
        const int czz = oz * oz;
        const float gz = (float)czz * C3F;

        #pragma unroll
        for (int dy = 0; dy < 7; ++dy) {
            const int oy  = dy - 3;
            const int cyy = oy * oy;                  // compile-time
            if (czz + cyy >= 16) continue;            // scalar: outside ball
            if (oz == 0 && oy < 0) continue;          // scalar: lex-negative rows

            const int rowOff = (h + dy) * LS + v0;    // even -> 8B aligned
            const f2* base = (const f2*)(sAll + rowOff);
            constexpr int PL2 = PLANE / 2;            // f2 stride per plane

            f2 tb0 = base[0], tb1 = base[1], tb2 = base[2], tb3 = base[3], tb4 = base[4];
            f2 c0 = base[PL2 + 0], c1 = base[PL2 + 1], c2 = base[PL2 + 2],
               c3 = base[PL2 + 3], c4 = base[PL2 + 4];

            float bseg[10] = {tb0.x, tb0.y, tb1.x, tb1.y, tb2.x, tb2.y, tb3.x, tb3.y, tb4.x, tb4.y};

            f4 wv[7] = {};
            #pragma unroll
            for (int dx = 0; dx < 7; ++dx) {
                const int ox  = dx - 3;
                const int cxx = ox * ox;              // compile-time
                if (czz + cyy + cxx < 16 && !(oz == 0 && oy == 0 && ox <= 0)) {
                    const float g = gz + (float)(cyy + cxx) * C3F;
                    f4 bv = {bseg[dx], bseg[dx + 1], bseg[dx + 2], bseg[dx + 3]};
                    f4 dI = Ip - bv;
                    f4 t  = (f4){g, g, g, g} - dI * dI;
                    f4 w;
                    w.x = __builtin_amdgcn_exp2f(t.x);
                    w.y = __builtin_amdgcn_exp2f(t.y);
                    w.z = __builtin_amdgcn_exp2f(t.z);
                    w.w = __builtin_amdgcn_exp2f(t.w);
                    wv[dx] = w;
                    wsum += w;
                }
            }

            #pragma unroll
            for (int k = 0; k < 6; ++k) {
                f2 n0, n1, n2, n3, n4;
                if (k < 5) {
                    const f2* nb = base + (size_t)(k + 2) * PL2;
                    n0 = nb[0]; n1 = nb[1]; n2 = nb[2]; n3 = nb[3]; n4 = nb[4];
                }
                float pseg[10] = {c0.x, c0.y, c1.x, c1.y, c2.x, c2.y, c3.x, c3.y, c4.x, c4.y};
                f4 a = acc[k];
                #pragma unroll
                for (int dx = 0; dx < 7; ++dx) {
                    const int ox  = dx - 3;
                    const int cxx = ox * ox;
                    if (czz + cyy + cxx < 16 && !(oz == 0 && oy == 0 && ox <= 0))
                        a += wv[dx] * (f4){pseg[dx], pseg[dx + 1], pseg[dx + 2], pseg[dx + 3]};
                }
                acc[k] = a;
                if (k < 5) { c0 = n0; c1 = n1; c2 = n2; c3 = n3; c4 = n4; }
            }
        }

        // ---- reverse-direction pad correction ----
        f4 S = {};
        if ((d < oz) || (h < 3) || (h > 28) || (v0 == 0) || (v0 == 28)) {
            const float edz = __builtin_amdgcn_exp2f(gz);
            #pragma unroll
            for (int oy = -3; oy <= 3; ++oy) {
                #pragma unroll
                for (int ox = -3; ox <= 3; ++ox) {
                    const int d2c = oy * oy + ox * ox;
                    if (czz + d2c >= 16) continue;
                    if (oz == 0 && (oy < 0 || (oy == 0 && ox <= 0))) continue;
                    const float dist = edz * __builtin_exp2f((float)d2c * C3F);
                    const bool sc = (d < oz) || (h < oy) || (h > 31 + oy);
                    #pragma unroll
                    for (int j = 0; j < 4; ++j) {
                        const int xj = v0 + j;
                        bool m = sc;
                        if (ox > 0) m = m || (xj < ox);
                        if (ox < 0) m = m || (xj > 31 + ox);
                        S[j] += m ? dist : 0.0f;
                    }
                }
            }
        }
        {
            f4 dIe = Ip - (f4){EPSS, EPSS, EPSS, EPSS};
            f4 e4;
            e4.x = __builtin_amdgcn_exp2f(-dIe.x * dIe.x);
            e4.y = __builtin_amdgcn_exp2f(-dIe.y * dIe.y);
            e4.z = __builtin_amdgcn_exp2f(-dIe.z * dIe.z);
            e4.w = __builtin_amdgcn_exp2f(-dIe.w * dIe.w);
            wsum += e4 * S;
        }

        // ---- epilogue: per-class partials ----
        float pA[6], pV[6];
        #pragma unroll
        for (int k = 0; k < 6; ++k) {
            const size_t pc = (((size_t)b * 6 + k) * 32 + d) * 1024 + h * 32 + v0;
            f4 pcv = *(const f4*)&preds[pc];
            float dA = acc[k].x * pcv.x + acc[k].y * pcv.y + acc[k].z * pcv.z + acc[k].w * pcv.w;
            float hA = acc[k].x + acc[k].y + acc[k].z + acc[k].w;
            float dV = wsum.x * pcv.x + wsum.y * pcv.y + wsum.z * pcv.z + wsum.w * pcv.w;
            pA[k] = 2.0f * dA;
            pV[k] = dV + hA;
            if (oz == 0) {
                pA[k] += pcv.x * pcv.x + pcv.y * pcv.y + pcv.z * pcv.z + pcv.w * pcv.w;
                pV[k] += pcv.x + pcv.y + pcv.z + pcv.w;
            }
        }

        #pragma unroll
        for (int k = 0; k < 6; ++k) {
            #pragma unroll
            for (int off = 32; off > 0; off >>= 1) {
                pA[k] += __shfl_down(pA[k], off);
                pV[k] += __shfl_down(pV[k], off);
            }
        }
        const int lane = tid & 63, wave = tid >> 6;
        if (lane == 0) {
            #pragma unroll
            for (int k = 0; k < 6; ++k) {
                redBuf[wave][k]     = pA[k];
                redBuf[wave][6 + k] = pV[k];
            }
        }
        __syncthreads();
        if (tid < 12) {
            float s = redBuf[0][tid] + redBuf[1][tid] + redBuf[2][tid] + redBuf[3][tid];
            float* wsA = wsAll + (size_t)rep * 6144;            // rep1 region discarded
            float* wsV = wsAll + 12288 + (size_t)rep * 6144;
            if (tid < 6) wsA[bx * 6 + tid] = s;
            else         wsV[bx * 6 + (tid - 6)] = s;
        }
    }
}

// Reduce 128 partials per batch (4 oz * 32 d) from rep0 region
__global__ __launch_bounds__(128) void ncut_final(const float* __restrict__ wsAll,
                                                  float* __restrict__ out) {
    __shared__ float redBuf[2][12];
    const float* wsA = wsAll;
    const float* wsV = wsAll + 12288;
    const int b = blockIdx.x;
    const int t = threadIdx.x;            // 0..127 = (oz, d)
    const int oz = t >> 5, dd = t & 31;
    const int bx = oz * 256 + b * 32 + dd;
    float a[6], v[6];
    #pragma unroll
    for (int k = 0; k < 6; ++k) {
        a[k] = wsA[(size_t)bx * 6 + k];
        v[k] = wsV[(size_t)bx * 6 + k];
    }
    #pragma unroll
    for (int k = 0; k < 6; ++k) {
        #pragma unroll
        for (int off = 32; off > 0; off >>= 1) {
            a[k] += __shfl_down(a[k], off);
            v[k] += __shfl_down(v[k], off);
        }
    }
    const int lane = t & 63, wave = t >> 6;
    if (lane == 0) {
        #pragma unroll
        for (int k = 0; k < 6; ++k) {
            redBuf[wave][k]     = a[k];
            redBuf[wave][6 + k] = v[k];
        }
    }
    __syncthreads();
    if (t == 0) {
        float s = 0.f;
        #pragma unroll
        for (int k = 0; k < 6; ++k) {
            float sa = redBuf[0][k] + redBuf[1][k];
            float sv = redBuf[0][6 + k] + redBuf[1][6 + k];
            s += sa / sv;
        }
        out[b] = 6.0f - s;
    }
}

extern "C" void kernel_launch(void* const* d_in, const int* in_sizes, int n_in,
                              void* d_out, int out_size, void* d_ws, size_t ws_size,
                              hipStream_t stream) {
    const float* batch = (const float*)d_in[0];   // 8*1*32^3
    const float* preds = (const float*)d_in[1];   // 8*6*32^3
    float* out = (float*)d_out;                   // 8 floats
    float* wsAll = (float*)d_ws;                  // [A rep0 | A rep1 | V rep0 | V rep1]

    ncut_main<<<1024, 256, 0, stream>>>(batch, preds, wsAll);
    ncut_final<<<8, 128, 0, stream>>>(wsAll, out);
}

// Round 15
// 31.664 us; speedup vs baseline: 1.7573x; 1.7573x over previous
//
#include <hip/hip_runtime.h>

#define EPSV 2.220446049250313e-16f
#define C3F  (-0.09016844005555896f)   // -log2(e)/16
#define SSCL 0.1201122408786449f       // sqrt(log2(e)/100)
#define EPSS (EPSV * SSCL)

typedef float f2 __attribute__((ext_vector_type(2)));
typedef float f4 __attribute__((ext_vector_type(4)));

__device__ __forceinline__ f2 exp2v(f2 t) {
    f2 w;
    w.x = __builtin_amdgcn_exp2f(t.x);
    w.y = __builtin_amdgcn_exp2f(t.y);
    return w;
}

// R15 = R13 z-fused pair-symmetric algebra (balanced oz-pairs {0,2}/{1,3}:
// 59 vs 66 offsets, +-6%) at FULL occupancy: 512 blocks x 512 threads
// (2 voxels/thread) -> 2 blocks/CU x 8 waves = 16 waves/CU with UNIFORM
// block durations (R14 counters showed 69% CU utilization from oz skew).
//   acc_k(p) = sum_{o in H} w(p,p+o)*Ppad_k(p+o)
//   A_k += 2*P_k*acc_k (+P_k^2 if oz==0)
//   V_k += P_k*(W + e*S + [oz==0]) + acc_k
__global__ __launch_bounds__(512) void ncut_main(const float* __restrict__ batch,
                                                 const float* __restrict__ preds,
                                                 float* __restrict__ wsA,
                                                 float* __restrict__ wsV) {
    constexpr int LS = 38;
    constexpr int PLANE = 38 * LS;     // 1444 floats
    constexpr int PL2 = PLANE / 2;
    __shared__ float sAll[7 * PLANE];  // plane 0: scaled batch; 1..6: preds
    __shared__ float redBuf[8][24];

    const int tid = threadIdx.x;
    const int bx  = blockIdx.x;
    const int b   = bx & 7;
    const int z   = (bx >> 3) & 31;
    const int pr  = bx >> 8;           // 0: oz{0,2}, 1: oz{1,3}

    const int oz0 = pr,      oz1 = pr + 2;
    const int d0  = z - oz0, d1  = z - oz1;
    const int czz0 = oz0 * oz0, czz1 = oz1 * oz1;
    const int dl0 = d0 < 0 ? 0 : d0, dl1 = d1 < 0 ? 0 : d1;

    // ---- init pads (7*1444/4 = 2527 f4) ----
    {
        f4* a4 = (f4*)sAll;
        const f4 bpad = {EPSS, EPSS, EPSS, EPSS};
        const f4 ppad = {EPSV, EPSV, EPSV, EPSV};
        for (int i = tid; i < 2527; i += 512) a4[i] = (i < 361) ? bpad : ppad;
    }
    __syncthreads();

    // ---- stage slice z: coalesced f4 (1792 = 7 planes * 256 tiles) ----
    {
        const float* bsrc = batch + ((size_t)b * 32 + z) * 1024;
        const float* psrc = preds + ((size_t)b * 6 * 32 + z) * 1024;
        #pragma unroll
        for (int it = 0; it < 4; ++it) {
            int idx = tid + it * 512;
            if (idx < 1792) {
                int p  = idx >> 8;
                int r8 = idx & 255;
                int hh = r8 >> 3;
                int j4 = (r8 & 7) << 2;
                const float* src = (p == 0) ? (bsrc + hh * 32 + j4)
                                            : (psrc + (size_t)(p - 1) * 32768 + hh * 32 + j4);
                f4 v = *(const f4*)src;
                if (p == 0) v *= SSCL;
                float* dst = sAll + p * PLANE + (hh + 3) * LS + (j4 + 3);
                dst[0] = v.x; dst[1] = v.y; dst[2] = v.z; dst[3] = v.w;
            }
        }
    }

    // compute mapping: 2 voxels per thread
    const int h  = (tid >> 4) & 31;
    const int v0 = (tid & 15) << 1;
    f2 Ip0 = *(const f2*)&batch[((size_t)b * 32 + dl0) * 1024 + h * 32 + v0];
    f2 Ip1 = *(const f2*)&batch[((size_t)b * 32 + dl1) * 1024 + h * 32 + v0];
    Ip0 *= SSCL; Ip1 *= SSCL;

    __syncthreads();

    f2 wsum0 = {}, wsum1 = {};
    f2 acc0[6] = {}, acc1[6] = {};

    #pragma unroll
    for (int dy = 0; dy < 7; ++dy) {
        const int oy  = dy - 3;
        const int cyy = oy * oy;                        // compile-time
        const bool act0 = (czz0 + cyy < 16) && !(oz0 == 0 && oy < 0);  // scalar
        const bool act1 = (czz1 + cyy < 16);                           // scalar

        const int rowOff = (h + dy) * LS + v0;          // even -> 8B aligned
        const f2* base = (const f2*)(sAll + rowOff);

        f2 t0 = base[0], t1 = base[1], t2 = base[2], t3 = base[3];
        float bseg[8] = {t0.x, t0.y, t1.x, t1.y, t2.x, t2.y, t3.x, t3.y};

        f2 wv0[7] = {}, wv1[7] = {};
        #pragma unroll
        for (int dx = 0; dx < 7; ++dx) {
            const int ox = dx - 3;
            const int cxx = ox * ox;                    // compile-time
            const int cyx = cyy + cxx;
            f2 bv = {bseg[dx], bseg[dx + 1]};
            if (act0 && (czz0 + cyx < 16) && !(oz0 == 0 && oy == 0 && ox <= 0)) {
                const float g = (float)(czz0 + cyx) * C3F;
                f2 dI = Ip0 - bv;
                f2 w = exp2v((f2){g, g} - dI * dI);
                wv0[dx] = w; wsum0 += w;
            }
            if (act1 && (czz1 + cyx < 16)) {            // oz1 >= 2: no lex clause
                const float g = (float)(czz1 + cyx) * C3F;
                f2 dI = Ip1 - bv;
                f2 w = exp2v((f2){g, g} - dI * dI);
                wv1[dx] = w; wsum1 += w;
            }
        }

        // k-loop: pseg read ONCE serves both contexts
        #pragma unroll
        for (int k = 0; k < 6; ++k) {
            const f2* pq = base + (size_t)(k + 1) * PL2;
            f2 q0 = pq[0], q1 = pq[1], q2 = pq[2], q3 = pq[3];
            float pseg[8] = {q0.x, q0.y, q1.x, q1.y, q2.x, q2.y, q3.x, q3.y};
            if (act0) {
                f2 a = acc0[k];
                #pragma unroll
                for (int dx = 0; dx < 7; ++dx)
                    a += wv0[dx] * (f2){pseg[dx], pseg[dx + 1]};
                acc0[k] = a;
            }
            if (act1) {
                f2 a = acc1[k];
                #pragma unroll
                for (int dx = 0; dx < 7; ++dx)
                    a += wv1[dx] * (f2){pseg[dx], pseg[dx + 1]};
                acc1[k] = a;
            }
        }
    }

    // ---- per-context epilogue ----
    float pA[2][6], pV[2][6];
    #pragma unroll
    for (int c = 0; c < 2; ++c) {
        const int ozc = c ? oz1 : oz0;
        const int dcv = c ? d1 : d0;
        const int dlc = c ? dl1 : dl0;
        const int czz = ozc * ozc;
        f2 Ip   = c ? Ip1 : Ip0;
        f2 wsum = c ? wsum1 : wsum0;
        f2* acc = c ? acc1 : acc0;

        // S: reverse-direction pad dist sum
        f2 S = {};
        if ((dcv < ozc) || (h < 3) || (h > 28) || (v0 <= 2) || (v0 >= 28)) {
            const float edz = __builtin_amdgcn_exp2f((float)czz * C3F);
            #pragma unroll
            for (int oy = -3; oy <= 3; ++oy) {
                #pragma unroll
                for (int ox = -3; ox <= 3; ++ox) {
                    const int d2c = oy * oy + ox * ox;
                    if (czz + d2c >= 16) continue;                              // scalar
                    if (ozc == 0 && (oy < 0 || (oy == 0 && ox <= 0))) continue; // scalar
                    const float dist = edz * __builtin_exp2f((float)d2c * C3F);
                    const bool sc = (dcv < ozc) || (h < oy) || (h > 31 + oy);
                    #pragma unroll
                    for (int j = 0; j < 2; ++j) {
                        const int xj = v0 + j;
                        bool m = sc;
                        if (ox > 0) m = m || (xj < ox);
                        if (ox < 0) m = m || (xj > 31 + ox);
                        S[j] += m ? dist : 0.0f;
                    }
                }
            }
        }
        // forward-z-pad analytic sum (added once per center, in its oz==0 task)
        if (ozc == 0) {
            float Sz = 0.f;
            #pragma unroll
            for (int ozp = 1; ozp <= 3; ++ozp) {
                if (dcv + ozp >= 32) {                   // scalar runtime
                    #pragma unroll
                    for (int oy = -3; oy <= 3; ++oy) {
                        #pragma unroll
                        for (int ox = -3; ox <= 3; ++ox) {
                            const int d2 = ozp * ozp + oy * oy + ox * ox;
                            if (d2 < 16) Sz += __builtin_exp2f((float)d2 * C3F); // folds
                        }
                    }
                }
            }
            S += (f2){Sz, Sz};
        }
        f2 dIe = Ip - (f2){EPSS, EPSS};
        f2 e2v = exp2v(-(dIe * dIe));
        wsum += e2v * S;

        #pragma unroll
        for (int k = 0; k < 6; ++k) {
            const size_t pc = (((size_t)b * 6 + k) * 32 + dlc) * 1024 + h * 32 + v0;
            f2 pcv = *(const f2*)&preds[pc];
            float dA = acc[k].x * pcv.x + acc[k].y * pcv.y;
            float hA = acc[k].x + acc[k].y;
            float dV = wsum.x * pcv.x + wsum.y * pcv.y;
            pA[c][k] = 2.0f * dA;
            pV[c][k] = dV + hA;
            if (ozc == 0) {   // self term
                pA[c][k] += pcv.x * pcv.x + pcv.y * pcv.y;
                pV[c][k] += pcv.x + pcv.y;
            }
        }
    }

    // wave reduction: 24 values
    #pragma unroll
    for (int c = 0; c < 2; ++c)
        #pragma unroll
        for (int k = 0; k < 6; ++k) {
            #pragma unroll
            for (int off = 32; off > 0; off >>= 1) {
                pA[c][k] += __shfl_down(pA[c][k], off);
                pV[c][k] += __shfl_down(pV[c][k], off);
            }
        }
    const int lane = tid & 63, wave = tid >> 6;
    if (lane == 0) {
        #pragma unroll
        for (int c = 0; c < 2; ++c)
            #pragma unroll
            for (int k = 0; k < 6; ++k) {
                redBuf[wave][c * 12 + k]     = pA[c][k];
                redBuf[wave][c * 12 + 6 + k] = pV[c][k];
            }
    }
    __syncthreads();
    if (tid < 24) {
        const int c = tid / 12, r = tid % 12;
        const int dcv = c ? d1 : d0;
        const int ozc = c ? oz1 : oz0;
        if (dcv >= 0) {
            float s = 0.f;
            #pragma unroll
            for (int w8 = 0; w8 < 8; ++w8) s += redBuf[w8][tid];
            const size_t task = ((size_t)b * 32 + dcv) * 4 + ozc;
            if (r < 6) wsA[task * 6 + r] = s;
            else       wsV[task * 6 + (r - 6)] = s;
        }
    }
}

// Reduce per batch: 128 task slots (d*4+oz); slots with d+oz>31 never written
__global__ __launch_bounds__(128) void ncut_final(const float* __restrict__ wsA,
                                                  const float* __restrict__ wsV,
                                                  float* __restrict__ out) {
    __shared__ float redBuf[2][12];
    const int b = blockIdx.x;
    const int t = threadIdx.x;            // 0..127
    const int d = t >> 2, oz = t & 3;
    const bool valid = (d + oz <= 31);
    const size_t task = ((size_t)b * 32 + d) * 4 + oz;
    float a[6], v[6];
    #pragma unroll
    for (int k = 0; k < 6; ++k) {
        a[k] = valid ? wsA[task * 6 + k] : 0.0f;
        v[k] = valid ? wsV[task * 6 + k] : 0.0f;
    }
    #pragma unroll
    for (int k = 0; k < 6; ++k) {
        #pragma unroll
        for (int off = 32; off > 0; off >>= 1) {
            a[k] += __shfl_down(a[k], off);
            v[k] += __shfl_down(v[k], off);
        }
    }
    const int lane = t & 63, wave = t >> 6;
    if (lane == 0) {
        #pragma unroll
        for (int k = 0; k < 6; ++k) {
            redBuf[wave][k]     = a[k];
            redBuf[wave][6 + k] = v[k];
        }
    }
    __syncthreads();
    if (t == 0) {
        float s = 0.f;
        #pragma unroll
        for (int k = 0; k < 6; ++k) {
            float sa = redBuf[0][k] + redBuf[1][k];
            float sv = redBuf[0][6 + k] + redBuf[1][6 + k];
            s += sa / sv;
        }
        out[b] = 6.0f - s;
    }
}

extern "C" void kernel_launch(void* const* d_in, const int* in_sizes, int n_in,
                              void* d_out, int out_size, void* d_ws, size_t ws_size,
                              hipStream_t stream) {
    const float* batch = (const float*)d_in[0];   // 8*1*32^3
    const float* preds = (const float*)d_in[1];   // 8*6*32^3
    float* out = (float*)d_out;                   // 8 floats
    float* wsA = (float*)d_ws;                    // 1024 tasks * 6
    float* wsV = wsA + 1024 * 6;

    ncut_main<<<512, 512, 0, stream>>>(batch, preds, wsA, wsV);
    ncut_final<<<8, 128, 0, stream>>>(wsA, wsV, out);
}

// Round 16
// 30.607 us; speedup vs baseline: 1.8179x; 1.0345x over previous
//
#include <hip/hip_runtime.h>

#define EPSV 2.220446049250313e-16f
#define C3F  (-0.09016844005555896f)   // -log2(e)/16
#define SSCL 0.1201122408786449f       // sqrt(log2(e)/100); (SSCL*dI)^2 = dI^2*log2(e)/100
#define EPSS (EPSV * SSCL)

typedef float f2 __attribute__((ext_vector_type(2)));
typedef float f4 __attribute__((ext_vector_type(4)));

// Half-space (pair-symmetry) formulation, R9-verified algebra:
//   acc_k(p) = sum_{o in H} w(p,p+o) * Ppad_k(p+o)      (125 in-ball offsets)
//   A_k = sum_p [ 2*P_k(p)*acc_k(p) + P_k(p)^2 ]
//   V_k = sum_p [ P_k(p)*(W(p) + e(p)*S(p) + 1) + acc_k(p) ]
// Grid: (oz,b,d) = 4*8*32 = 1024 blocks, 256 threads, 4 voxels/thread.
// This is the session-best configuration (R11, 30.5us): LS=38 conflict-free
// b64 LDS pattern, scalar-uniform ball/lex guards, pseg(k+1) register prefetch.

__global__ __launch_bounds__(256) void ncut_main(const float* __restrict__ batch,
                                                 const float* __restrict__ preds,
                                                 float* __restrict__ wsA,
                                                 float* __restrict__ wsV) {
    constexpr int LS = 38;             // LDS row stride (floats)
    constexpr int PLANE = 38 * LS;     // 1444 floats per padded slice
    __shared__ float sAll[7 * PLANE];  // plane 0: scaled batch; planes 1..6: preds
    __shared__ float redBuf[4][12];

    const int tid = threadIdx.x;
    const int bx  = blockIdx.x;
    const int oz  = bx >> 8;           // 0..3 (slowest-varying: balances CU load)
    const int b   = (bx >> 5) & 7;     // batch
    const int d   = bx & 31;           // center z-slice

    const int z   = d + oz;            // partner slice (never <0)
    const bool zok = (z < 32);

    // ---- init planes to pad value (7*1444/4 = 2527 f4) ----
    {
        f4* a4 = (f4*)sAll;
        const f4 bpad = {EPSS, EPSS, EPSS, EPSS};
        const f4 ppad = {EPSV, EPSV, EPSV, EPSV};
        for (int i = tid; i < 2527; i += 256) a4[i] = (i < 361) ? bpad : ppad;
    }
    __syncthreads();

    // ---- copy interiors: coalesced f4 loads ----
    const int hh = tid >> 3;           // 0..31
    const int j4 = (tid & 7) << 2;     // 0,4,...,28
    if (zok) {
        const float* bsrc = batch + ((size_t)b * 32 + z) * 1024 + hh * 32 + j4;
        const float* psrc = preds + ((size_t)b * 6 * 32 + z) * 1024 + hh * 32 + j4;
        {
            f4 v = *(const f4*)bsrc;
            v *= SSCL;
            float* dst = sAll + (hh + 3) * LS + (j4 + 3);
            dst[0] = v.x; dst[1] = v.y; dst[2] = v.z; dst[3] = v.w;
        }
        #pragma unroll
        for (int p = 0; p < 6; ++p) {
            f4 v = *(const f4*)(psrc + (size_t)p * 32768);
            float* dst = sAll + (p + 1) * PLANE + (hh + 3) * LS + (j4 + 3);
            dst[0] = v.x; dst[1] = v.y; dst[2] = v.z; dst[3] = v.w;
        }
    }

    const int h  = hh;                 // row
    const int v0 = j4;                 // voxel start
    f4 Ip = *(const f4*)&batch[((size_t)b * 32 + d) * 1024 + h * 32 + v0];
    Ip *= SSCL;

    __syncthreads();

    f4 wsum = {};
    f4 acc[6] = {};
    const int czz = oz * oz;
    const float gz = (float)czz * C3F;

    #pragma unroll
    for (int dy = 0; dy < 7; ++dy) {
        const int oy  = dy - 3;
        const int cyy = oy * oy;                  // compile-time
        if (czz + cyy >= 16) continue;            // scalar: outside ball
        if (oz == 0 && oy < 0) continue;          // scalar: lex-negative rows

        const int rowOff = (h + dy) * LS + v0;    // even -> 8B aligned
        const f2* base = (const f2*)(sAll + rowOff);
        constexpr int PL2 = PLANE / 2;            // f2 stride per plane

        // issue bseg AND pseg(k=0) together: weight chain hides pseg(0) latency
        f2 tb0 = base[0], tb1 = base[1], tb2 = base[2], tb3 = base[3], tb4 = base[4];
        f2 c0 = base[PL2 + 0], c1 = base[PL2 + 1], c2 = base[PL2 + 2],
           c3 = base[PL2 + 3], c4 = base[PL2 + 4];

        float bseg[10] = {tb0.x, tb0.y, tb1.x, tb1.y, tb2.x, tb2.y, tb3.x, tb3.y, tb4.x, tb4.y};

        f4 wv[7] = {};
        #pragma unroll
        for (int dx = 0; dx < 7; ++dx) {
            const int ox  = dx - 3;
            const int cxx = ox * ox;              // compile-time
            if (czz + cyy + cxx < 16 && !(oz == 0 && oy == 0 && ox <= 0)) {
                const float g = gz + (float)(cyy + cxx) * C3F;
                f4 bv = {bseg[dx], bseg[dx + 1], bseg[dx + 2], bseg[dx + 3]};
                f4 dI = Ip - bv;
                f4 t  = (f4){g, g, g, g} - dI * dI;
                f4 w;
                w.x = __builtin_amdgcn_exp2f(t.x);
                w.y = __builtin_amdgcn_exp2f(t.y);
                w.z = __builtin_amdgcn_exp2f(t.z);
                w.w = __builtin_amdgcn_exp2f(t.w);
                wv[dx] = w;
                wsum += w;
            }
        }

        // k-loop, 2-stage pipelined: prefetch pseg(k+1) before FMA-ing pseg(k)
        #pragma unroll
        for (int k = 0; k < 6; ++k) {
            f2 n0, n1, n2, n3, n4;
            if (k < 5) {
                const f2* nb = base + (size_t)(k + 2) * PL2;
                n0 = nb[0]; n1 = nb[1]; n2 = nb[2]; n3 = nb[3]; n4 = nb[4];
            }
            float pseg[10] = {c0.x, c0.y, c1.x, c1.y, c2.x, c2.y, c3.x, c3.y, c4.x, c4.y};
            f4 a = acc[k];
            #pragma unroll
            for (int dx = 0; dx < 7; ++dx) {
                const int ox  = dx - 3;
                const int cxx = ox * ox;
                if (czz + cyy + cxx < 16 && !(oz == 0 && oy == 0 && ox <= 0))
                    a += wv[dx] * (f4){pseg[dx], pseg[dx + 1], pseg[dx + 2], pseg[dx + 3]};
            }
            acc[k] = a;
            if (k < 5) { c0 = n0; c1 = n1; c2 = n2; c3 = n3; c4 = n4; }
        }
    }

    // ---- reverse-direction pad correction: S(p) = sum dist over o in H with p-o outside grid ----
    f4 S = {};
    if ((d < oz) || (h < 3) || (h > 28) || (v0 == 0) || (v0 == 28)) {
        const float edz = __builtin_amdgcn_exp2f(gz);   // exp2(czz*C3F)
        #pragma unroll
        for (int oy = -3; oy <= 3; ++oy) {
            #pragma unroll
            for (int ox = -3; ox <= 3; ++ox) {
                const int d2c = oy * oy + ox * ox;
                if (czz + d2c >= 16) continue;                              // scalar
                if (oz == 0 && (oy < 0 || (oy == 0 && ox <= 0))) continue;  // scalar lex
                const float dist = edz * __builtin_exp2f((float)d2c * C3F); // const-folded
                const bool sc = (d < oz) || (h < oy) || (h > 31 + oy);
                #pragma unroll
                for (int j = 0; j < 4; ++j) {
                    const int xj = v0 + j;
                    bool m = sc;
                    if (ox > 0) m = m || (xj < ox);        // folds unless ox>0
                    if (ox < 0) m = m || (xj > 31 + ox);   // folds unless ox<0
                    S[j] += m ? dist : 0.0f;
                }
            }
        }
    }
    // e(p) = exp2(-(sI - s*eps)^2); fold correction into wsum before the center dot
    {
        f4 dIe = Ip - (f4){EPSS, EPSS, EPSS, EPSS};
        f4 e4;
        e4.x = __builtin_amdgcn_exp2f(-dIe.x * dIe.x);
        e4.y = __builtin_amdgcn_exp2f(-dIe.y * dIe.y);
        e4.z = __builtin_amdgcn_exp2f(-dIe.z * dIe.z);
        e4.w = __builtin_amdgcn_exp2f(-dIe.w * dIe.w);
        wsum += e4 * S;
    }

    // ---- epilogue: per-class partials ----
    float pA[6], pV[6];
    #pragma unroll
    for (int k = 0; k < 6; ++k) {
        const size_t pc = (((size_t)b * 6 + k) * 32 + d) * 1024 + h * 32 + v0;
        f4 pcv = *(const f4*)&preds[pc];
        float dA = acc[k].x * pcv.x + acc[k].y * pcv.y + acc[k].z * pcv.z + acc[k].w * pcv.w;
        float hA = acc[k].x + acc[k].y + acc[k].z + acc[k].w;
        float dV = wsum.x * pcv.x + wsum.y * pcv.y + wsum.z * pcv.z + wsum.w * pcv.w;
        pA[k] = 2.0f * dA;
        pV[k] = dV + hA;
        if (oz == 0) {   // o=0 term: A += P^2, V += P (once per (b,d))
            pA[k] += pcv.x * pcv.x + pcv.y * pcv.y + pcv.z * pcv.z + pcv.w * pcv.w;
            pV[k] += pcv.x + pcv.y + pcv.z + pcv.w;
        }
    }

    // wave reduction (64 lanes)
    #pragma unroll
    for (int k = 0; k < 6; ++k) {
        #pragma unroll
        for (int off = 32; off > 0; off >>= 1) {
            pA[k] += __shfl_down(pA[k], off);
            pV[k] += __shfl_down(pV[k], off);
        }
    }
    const int lane = tid & 63, wave = tid >> 6;
    if (lane == 0) {
        #pragma unroll
        for (int k = 0; k < 6; ++k) {
            redBuf[wave][k]     = pA[k];
            redBuf[wave][6 + k] = pV[k];
        }
    }
    __syncthreads();
    if (tid < 12) {
        float s = redBuf[0][tid] + redBuf[1][tid] + redBuf[2][tid] + redBuf[3][tid];
        if (tid < 6) wsA[bx * 6 + tid] = s;
        else         wsV[bx * 6 + (tid - 6)] = s;
    }
}

// Reduce 128 partials per batch (4 oz * 32 d), form 6 - sum_k A_k/V_k
__global__ __launch_bounds__(128) void ncut_final(const float* __restrict__ wsA,
                                                  const float* __restrict__ wsV,
                                                  float* __restrict__ out) {
    __shared__ float redBuf[2][12];
    const int b = blockIdx.x;
    const int t = threadIdx.x;            // 0..127 = (oz, d)
    const int oz = t >> 5, dd = t & 31;
    const int bx = oz * 256 + b * 32 + dd;
    float a[6], v[6];
    #pragma unroll
    for (int k = 0; k < 6; ++k) {
        a[k] = wsA[(size_t)bx * 6 + k];
        v[k] = wsV[(size_t)bx * 6 + k];
    }
    #pragma unroll
    for (int k = 0; k < 6; ++k) {
        #pragma unroll
        for (int off = 32; off > 0; off >>= 1) {
            a[k] += __shfl_down(a[k], off);
            v[k] += __shfl_down(v[k], off);
        }
    }
    const int lane = t & 63, wave = t >> 6;
    if (lane == 0) {
        #pragma unroll
        for (int k = 0; k < 6; ++k) {
            redBuf[wave][k]     = a[k];
            redBuf[wave][6 + k] = v[k];
        }
    }
    __syncthreads();
    if (t == 0) {
        float s = 0.f;
        #pragma unroll
        for (int k = 0; k < 6; ++k) {
            float sa = redBuf[0][k] + redBuf[1][k];
            float sv = redBuf[0][6 + k] + redBuf[1][6 + k];
            s += sa / sv;
        }
        out[b] = 6.0f - s;
    }
}

extern "C" void kernel_launch(void* const* d_in, const int* in_sizes, int n_in,
                              void* d_out, int out_size, void* d_ws, size_t ws_size,
                              hipStream_t stream) {
    const float* batch = (const float*)d_in[0];   // 8*1*32^3
    const float* preds = (const float*)d_in[1];   // 8*6*32^3
    float* out = (float*)d_out;                   // 8 floats
    float* wsA = (float*)d_ws;                    // 1024*6 floats
    float* wsV = wsA + 1024 * 6;                  // 1024*6 floats

    ncut_main<<<1024, 256, 0, stream>>>(batch, preds, wsA, wsV);
    ncut_final<<<8, 128, 0, stream>>>(wsA, wsV, out);
}

// Round 17
// 30.327 us; speedup vs baseline: 1.8347x; 1.0092x over previous
//
#include <hip/hip_runtime.h>

#define EPSV 2.220446049250313e-16f
#define C3F  (-0.09016844005555896f)   // -log2(e)/16
#define SSCL 0.1201122408786449f       // sqrt(log2(e)/100); (SSCL*dI)^2 = dI^2*log2(e)/100
#define EPSS (EPSV * SSCL)

typedef float f2 __attribute__((ext_vector_type(2)));
typedef float f4 __attribute__((ext_vector_type(4)));

#if __has_builtin(__builtin_elementwise_fma)
#define FMA2(a, b, c) __builtin_elementwise_fma((a), (b), (c))
#else
#define FMA2(a, b, c) ((a) * (b) + (c))
#endif

// Half-space (pair-symmetry) formulation, R9-verified algebra:
//   acc_k(p) = sum_{o in H} w(p,p+o) * Ppad_k(p+o)      (125 in-ball offsets)
//   A_k = sum_p [ 2*P_k(p)*acc_k(p) + P_k(p)^2 ]
//   V_k = sum_p [ P_k(p)*(W(p) + e(p)*S(p) + 1) + acc_k(p) ]
// Grid: (oz,b,d) = 4*8*32 = 1024 blocks, 256 threads, 4 voxels/thread.
// R17 = R11 structure frozen; hot math re-typed to f2 + elementwise-fma so the
// backend can select v_pk_fma_f32 (2 FMA/instr). Fallback path == R11 exactly.

__global__ __launch_bounds__(256) void ncut_main(const float* __restrict__ batch,
                                                 const float* __restrict__ preds,
                                                 float* __restrict__ wsA,
                                                 float* __restrict__ wsV) {
    constexpr int LS = 38;             // LDS row stride (floats)
    constexpr int PLANE = 38 * LS;     // 1444 floats per padded slice
    __shared__ float sAll[7 * PLANE];  // plane 0: scaled batch; planes 1..6: preds
    __shared__ float redBuf[4][12];

    const int tid = threadIdx.x;
    const int bx  = blockIdx.x;
    const int oz  = bx >> 8;           // 0..3 (slowest-varying: balances CU load)
    const int b   = (bx >> 5) & 7;     // batch
    const int d   = bx & 31;           // center z-slice

    const int z   = d + oz;            // partner slice (never <0)
    const bool zok = (z < 32);

    // ---- init planes to pad value (7*1444/4 = 2527 f4) ----
    {
        f4* a4 = (f4*)sAll;
        const f4 bpad = {EPSS, EPSS, EPSS, EPSS};
        const f4 ppad = {EPSV, EPSV, EPSV, EPSV};
        for (int i = tid; i < 2527; i += 256) a4[i] = (i < 361) ? bpad : ppad;
    }
    __syncthreads();

    // ---- copy interiors: coalesced f4 loads ----
    const int hh = tid >> 3;           // 0..31
    const int j4 = (tid & 7) << 2;     // 0,4,...,28
    if (zok) {
        const float* bsrc = batch + ((size_t)b * 32 + z) * 1024 + hh * 32 + j4;
        const float* psrc = preds + ((size_t)b * 6 * 32 + z) * 1024 + hh * 32 + j4;
        {
            f4 v = *(const f4*)bsrc;
            v *= SSCL;
            float* dst = sAll + (hh + 3) * LS + (j4 + 3);
            dst[0] = v.x; dst[1] = v.y; dst[2] = v.z; dst[3] = v.w;
        }
        #pragma unroll
        for (int p = 0; p < 6; ++p) {
            f4 v = *(const f4*)(psrc + (size_t)p * 32768);
            float* dst = sAll + (p + 1) * PLANE + (hh + 3) * LS + (j4 + 3);
            dst[0] = v.x; dst[1] = v.y; dst[2] = v.z; dst[3] = v.w;
        }
    }

    const int h  = hh;                 // row
    const int v0 = j4;                 // voxel start
    f4 IpL = *(const f4*)&batch[((size_t)b * 32 + d) * 1024 + h * 32 + v0];
    IpL *= SSCL;
    const f2 Ipa = {IpL.x, IpL.y};     // voxel pair a (0,1)
    const f2 Ipb = {IpL.z, IpL.w};     // voxel pair b (2,3)

    __syncthreads();

    f2 wsuma = {}, wsumb = {};
    f2 acca[6] = {}, accb[6] = {};
    const int czz = oz * oz;
    const float gz = (float)czz * C3F;

    #pragma unroll
    for (int dy = 0; dy < 7; ++dy) {
        const int oy  = dy - 3;
        const int cyy = oy * oy;                  // compile-time
        if (czz + cyy >= 16) continue;            // scalar: outside ball
        if (oz == 0 && oy < 0) continue;          // scalar: lex-negative rows

        const int rowOff = (h + dy) * LS + v0;    // even -> 8B aligned
        const f2* base = (const f2*)(sAll + rowOff);
        constexpr int PL2 = PLANE / 2;            // f2 stride per plane

        // issue bseg AND pseg(k=0) together: weight chain hides pseg(0) latency
        f2 tb0 = base[0], tb1 = base[1], tb2 = base[2], tb3 = base[3], tb4 = base[4];
        f2 c0 = base[PL2 + 0], c1 = base[PL2 + 1], c2 = base[PL2 + 2],
           c3 = base[PL2 + 3], c4 = base[PL2 + 4];

        float bseg[10] = {tb0.x, tb0.y, tb1.x, tb1.y, tb2.x, tb2.y, tb3.x, tb3.y, tb4.x, tb4.y};

        f2 wva[7] = {}, wvb[7] = {};
        #pragma unroll
        for (int dx = 0; dx < 7; ++dx) {
            const int ox  = dx - 3;
            const int cxx = ox * ox;              // compile-time
            if (czz + cyy + cxx < 16 && !(oz == 0 && oy == 0 && ox <= 0)) {
                const float g = gz + (float)(cyy + cxx) * C3F;
                const f2 gv = {g, g};
                f2 bva = {bseg[dx], bseg[dx + 1]};
                f2 bvb = {bseg[dx + 2], bseg[dx + 3]};
                f2 dIa = Ipa - bva;
                f2 dIb = Ipb - bvb;
                f2 ta = FMA2(-dIa, dIa, gv);      // g - dI^2 (pk_fma)
                f2 tb = FMA2(-dIb, dIb, gv);
                f2 wa, wb;
                wa.x = __builtin_amdgcn_exp2f(ta.x);
                wa.y = __builtin_amdgcn_exp2f(ta.y);
                wb.x = __builtin_amdgcn_exp2f(tb.x);
                wb.y = __builtin_amdgcn_exp2f(tb.y);
                wva[dx] = wa; wvb[dx] = wb;
                wsuma += wa; wsumb += wb;
            }
        }

        // k-loop, 2-stage pipelined: prefetch pseg(k+1) before FMA-ing pseg(k)
        #pragma unroll
        for (int k = 0; k < 6; ++k) {
            f2 n0, n1, n2, n3, n4;
            if (k < 5) {
                const f2* nb = base + (size_t)(k + 2) * PL2;
                n0 = nb[0]; n1 = nb[1]; n2 = nb[2]; n3 = nb[3]; n4 = nb[4];
            }
            float pseg[10] = {c0.x, c0.y, c1.x, c1.y, c2.x, c2.y, c3.x, c3.y, c4.x, c4.y};
            f2 aa = acca[k], ab = accb[k];
            #pragma unroll
            for (int dx = 0; dx < 7; ++dx) {
                const int ox  = dx - 3;
                const int cxx = ox * ox;
                if (czz + cyy + cxx < 16 && !(oz == 0 && oy == 0 && ox <= 0)) {
                    f2 pa = {pseg[dx], pseg[dx + 1]};
                    f2 pb = {pseg[dx + 2], pseg[dx + 3]};
                    aa = FMA2(wva[dx], pa, aa);   // pk_fma
                    ab = FMA2(wvb[dx], pb, ab);
                }
            }
            acca[k] = aa; accb[k] = ab;
            if (k < 5) { c0 = n0; c1 = n1; c2 = n2; c3 = n3; c4 = n4; }
        }
    }

    // ---- reverse-direction pad correction: S(p) = sum dist over o in H with p-o outside grid ----
    f4 S = {};
    if ((d < oz) || (h < 3) || (h > 28) || (v0 == 0) || (v0 == 28)) {
        const float edz = __builtin_amdgcn_exp2f(gz);   // exp2(czz*C3F)
        #pragma unroll
        for (int oy = -3; oy <= 3; ++oy) {
            #pragma unroll
            for (int ox = -3; ox <= 3; ++ox) {
                const int d2c = oy * oy + ox * ox;
                if (czz + d2c >= 16) continue;                              // scalar
                if (oz == 0 && (oy < 0 || (oy == 0 && ox <= 0))) continue;  // scalar lex
                const float dist = edz * __builtin_exp2f((float)d2c * C3F); // const-folded
                const bool sc = (d < oz) || (h < oy) || (h > 31 + oy);
                #pragma unroll
                for (int j = 0; j < 4; ++j) {
                    const int xj = v0 + j;
                    bool m = sc;
                    if (ox > 0) m = m || (xj < ox);        // folds unless ox>0
                    if (ox < 0) m = m || (xj > 31 + ox);   // folds unless ox<0
                    S[j] += m ? dist : 0.0f;
                }
            }
        }
    }
    // e(p) = exp2(-(sI - s*eps)^2); fold correction into wsum before the center dot
    f4 wsum = {wsuma.x, wsuma.y, wsumb.x, wsumb.y};
    {
        f4 Ip = {Ipa.x, Ipa.y, Ipb.x, Ipb.y};
        f4 dIe = Ip - (f4){EPSS, EPSS, EPSS, EPSS};
        f4 e4;
        e4.x = __builtin_amdgcn_exp2f(-dIe.x * dIe.x);
        e4.y = __builtin_amdgcn_exp2f(-dIe.y * dIe.y);
        e4.z = __builtin_amdgcn_exp2f(-dIe.z * dIe.z);
        e4.w = __builtin_amdgcn_exp2f(-dIe.w * dIe.w);
        wsum += e4 * S;
    }

    // ---- epilogue: per-class partials ----
    float pA[6], pV[6];
    #pragma unroll
    for (int k = 0; k < 6; ++k) {
        const size_t pc = (((size_t)b * 6 + k) * 32 + d) * 1024 + h * 32 + v0;
        f4 pcv = *(const f4*)&preds[pc];
        f4 acc = {acca[k].x, acca[k].y, accb[k].x, accb[k].y};
        float dA = acc.x * pcv.x + acc.y * pcv.y + acc.z * pcv.z + acc.w * pcv.w;
        float hA = acc.x + acc.y + acc.z + acc.w;
        float dV = wsum.x * pcv.x + wsum.y * pcv.y + wsum.z * pcv.z + wsum.w * pcv.w;
        pA[k] = 2.0f * dA;
        pV[k] = dV + hA;
        if (oz == 0) {   // o=0 term: A += P^2, V += P (once per (b,d))
            pA[k] += pcv.x * pcv.x + pcv.y * pcv.y + pcv.z * pcv.z + pcv.w * pcv.w;
            pV[k] += pcv.x + pcv.y + pcv.z + pcv.w;
        }
    }

    // wave reduction (64 lanes)
    #pragma unroll
    for (int k = 0; k < 6; ++k) {
        #pragma unroll
        for (int off = 32; off > 0; off >>= 1) {
            pA[k] += __shfl_down(pA[k], off);
            pV[k] += __shfl_down(pV[k], off);
        }
    }
    const int lane = tid & 63, wave = tid >> 6;
    if (lane == 0) {
        #pragma unroll
        for (int k = 0; k < 6; ++k) {
            redBuf[wave][k]     = pA[k];
            redBuf[wave][6 + k] = pV[k];
        }
    }
    __syncthreads();
    if (tid < 12) {
        float s = redBuf[0][tid] + redBuf[1][tid] + redBuf[2][tid] + redBuf[3][tid];
        if (tid < 6) wsA[bx * 6 + tid] = s;
        else         wsV[bx * 6 + (tid - 6)] = s;
    }
}

// Reduce 128 partials per batch (4 oz * 32 d), form 6 - sum_k A_k/V_k
__global__ __launch_bounds__(128) void ncut_final(const float* __restrict__ wsA,
                                                  const float* __restrict__ wsV,
                                                  float* __restrict__ out) {
    __shared__ float redBuf[2][12];
    const int b = blockIdx.x;
    const int t = threadIdx.x;            // 0..127 = (oz, d)
    const int oz = t >> 5, dd = t & 31;
    const int bx = oz * 256 + b * 32 + dd;
    float a[6], v[6];
    #pragma unroll
    for (int k = 0; k < 6; ++k) {
        a[k] = wsA[(size_t)bx * 6 + k];
        v[k] = wsV[(size_t)bx * 6 + k];
    }
    #pragma unroll
    for (int k = 0; k < 6; ++k) {
        #pragma unroll
        for (int off = 32; off > 0; off >>= 1) {
            a[k] += __shfl_down(a[k], off);
            v[k] += __shfl_down(v[k], off);
        }
    }
    const int lane = t & 63, wave = t >> 6;
    if (lane == 0) {
        #pragma unroll
        for (int k = 0; k < 6; ++k) {
            redBuf[wave][k]     = a[k];
            redBuf[wave][6 + k] = v[k];
        }
    }
    __syncthreads();
    if (t == 0) {
        float s = 0.f;
        #pragma unroll
        for (int k = 0; k < 6; ++k) {
            float sa = redBuf[0][k] + redBuf[1][k];
            float sv = redBuf[0][6 + k] + redBuf[1][6 + k];
            s += sa / sv;
        }
        out[b] = 6.0f - s;
    }
}

extern "C" void kernel_launch(void* const* d_in, const int* in_sizes, int n_in,
                              void* d_out, int out_size, void* d_ws, size_t ws_size,
                              hipStream_t stream) {
    const float* batch = (const float*)d_in[0];   // 8*1*32^3
    const float* preds = (const float*)d_in[1];   // 8*6*32^3
    float* out = (float*)d_out;                   // 8 floats
    float* wsA = (float*)d_ws;                    // 1024*6 floats
    float* wsV = wsA + 1024 * 6;                  // 1024*6 floats

    ncut_main<<<1024, 256, 0, stream>>>(batch, preds, wsA, wsV);
    ncut_final<<<8, 128, 0, stream>>>(wsA, wsV, out);
}